// Round 2
// baseline (226.053 us; speedup 1.0000x reference)
//
#include <hip/hip_runtime.h>
#include <hip/hip_bf16.h>

typedef __attribute__((ext_vector_type(4))) float f32x4;
typedef __attribute__((ext_vector_type(8))) short bf16x8;

// ---- workspace layout (bytes) ----
#define OFF_QS    0ull                     // [131072][128] bf16  q softmaxed * 1/sqrt(32)
#define OFF_EK    33554432ull              // [131072][128] bf16  exp(k)
#define OFF_VV    67108864ull              // [131072][128] bf16  v (raw)
#define OFF_PCTX  100663296ull             // [16][128][32][32] f32 chunk partials
#define OFF_PSE   109051904ull             // [16][128][32] f32 chunk sum-exp
#define OFF_CTXG  109314048ull             // [32][4][32][32] bf16 normalized ctx
#define OFF_WQT   109576192ull             // [384][128] bf16 (W_qkv^T)
#define OFF_WOT   109674496ull             // [128][128] bf16 (W_out^T)
// total 109707264 bytes (~104.6 MiB)

static __device__ __forceinline__ unsigned short f2bf(float f) {
  unsigned int u = __builtin_bit_cast(unsigned int, f);
  return (unsigned short)((u + 0x7fffu + ((u >> 16) & 1u)) >> 16);  // RNE
}

static __device__ __forceinline__ void unpack8(uint4 u, float* p) {
  p[0] = __builtin_bit_cast(float, u.x << 16);
  p[1] = __builtin_bit_cast(float, u.x & 0xffff0000u);
  p[2] = __builtin_bit_cast(float, u.y << 16);
  p[3] = __builtin_bit_cast(float, u.y & 0xffff0000u);
  p[4] = __builtin_bit_cast(float, u.z << 16);
  p[5] = __builtin_bit_cast(float, u.z & 0xffff0000u);
  p[6] = __builtin_bit_cast(float, u.w << 16);
  p[7] = __builtin_bit_cast(float, u.w & 0xffff0000u);
}

// ---------------- k_prep: weights -> bf16, transposed for B-fragments ----------------
__global__ __launch_bounds__(256) void k_prep(const float* __restrict__ wqkv,
                                              const float* __restrict__ wout,
                                              unsigned short* __restrict__ wqT,
                                              unsigned short* __restrict__ woT) {
  int idx = blockIdx.x * 256 + threadIdx.x;   // grid covers exactly 65536
  if (idx < 49152) {                          // wqT[f][k] = wqkv[k][f]
    int f = idx >> 7, k = idx & 127;
    wqT[idx] = f2bf(wqkv[k * 384 + f]);
  } else {                                    // woT[c][k] = wout[k][c]
    int j = idx - 49152;
    int c = j >> 7, k = j & 127;
    woT[j] = f2bf(wout[k * 128 + c]);
  }
}

// ---------------- k_qkv: x@Wqkv + q-softmax + exp(k); 128 rows/block ----------------
__global__ __launch_bounds__(512, 2) void k_qkv(const float* __restrict__ x,
                                                const unsigned short* __restrict__ wqT,
                                                unsigned short* __restrict__ qs,
                                                unsigned short* __restrict__ ek,
                                                unsigned short* __restrict__ vv) {
  extern __shared__ char lds[];
  char* lds_w = lds;            // [384][128] bf16, XOR-swizzled, 98304 B
  char* lds_a = lds + 98304;    // [128][128] bf16, XOR-swizzled, 32768 B

  const int tid = threadIdx.x;
  const long rowbase = (long)blockIdx.x * 128;

  {  // stage W (bf16, 16B units); swizzle XOR bits 4-6 with row f (G4)
    const int4* src = (const int4*)wqT;
    int4* dst = (int4*)lds_w;
#pragma unroll
    for (int i = 0; i < 12; i++) {
      int u = tid + i * 512;                 // row f = u>>4 (16 units/row)
      dst[u ^ ((u >> 4) & 7)] = src[u];
    }
  }
  {  // stage A: f32 -> bf16 (8B units); row = u>>5
    const f32x4* src = (const f32x4*)(x + rowbase * 128);
#pragma unroll
    for (int i = 0; i < 8; i++) {
      int u = tid + i * 512;
      f32x4 val = src[u];
      ushort4 bq;
      bq.x = f2bf(val.x); bq.y = f2bf(val.y); bq.z = f2bf(val.z); bq.w = f2bf(val.w);
      int ba = (u * 8) ^ (((u >> 5) & 7) << 4);
      *(ushort4*)(lds_a + ba) = bq;
    }
  }
  __syncthreads();

  const int lane = tid & 63;
  const int g = lane >> 4, c = lane & 15;
  const int wave = tid >> 6;
  const int wm = wave >> 2, wf = wave & 3;   // rows [64*wm,+64) x cols [96*wf,+96)

  f32x4 acc[4][6];
#pragma unroll
  for (int mt = 0; mt < 4; mt++)
#pragma unroll
    for (int ft = 0; ft < 6; ft++)
      acc[mt][ft] = (f32x4){0.f, 0.f, 0.f, 0.f};

#pragma unroll
  for (int kk = 0; kk < 4; kk++) {
    const int koff = (kk * 32 + g * 8) * 2;
    bf16x8 af[4], bfrag[6];
#pragma unroll
    for (int mt = 0; mt < 4; mt++) {
      int row = wm * 64 + mt * 16 + c;
      af[mt] = *(const bf16x8*)(lds_a + ((row * 256 + koff) ^ ((row & 7) << 4)));
    }
#pragma unroll
    for (int ft = 0; ft < 6; ft++) {
      int frow = wf * 96 + ft * 16 + c;
      bfrag[ft] = *(const bf16x8*)(lds_w + ((frow * 256 + koff) ^ ((frow & 7) << 4)));
    }
#pragma unroll
    for (int mt = 0; mt < 4; mt++)
#pragma unroll
      for (int ft = 0; ft < 6; ft++)
        acc[mt][ft] = __builtin_amdgcn_mfma_f32_16x16x32_bf16(af[mt], bfrag[ft], acc[mt][ft], 0, 0, 0);
  }

  // epilogue: 3 chunks of 32 cols per wave; each chunk = one (section, head)
  const float RS32 = 0.17677669529663687f;   // 1/sqrt(32)
#pragma unroll
  for (int ch = 0; ch < 3; ch++) {
    int gc = wf * 96 + ch * 32;
    int sec = gc >> 7;                       // 0=q 1=k 2=v (wave-uniform)
    int sc = gc & 127;
    unsigned short* dstp = (sec == 0) ? qs : (sec == 1 ? ek : vv);
#pragma unroll
    for (int mt = 0; mt < 4; mt++) {
      f32x4 a0 = acc[mt][2 * ch];
      f32x4 a1 = acc[mt][2 * ch + 1];
      long row0 = rowbase + wm * 64 + mt * 16 + g * 4;
      if (sec == 0) {                        // softmax over the head's 32 dims, in-register
#pragma unroll
        for (int r = 0; r < 4; r++) {
          float e0 = __expf(a0[r]), e1 = __expf(a1[r]);
          float s = e0 + e1;
          s += __shfl_xor(s, 1); s += __shfl_xor(s, 2);
          s += __shfl_xor(s, 4); s += __shfl_xor(s, 8);
          float inv = RS32 / s;
          long base = (row0 + r) * 128 + sc + c;
          dstp[base]      = f2bf(e0 * inv);
          dstp[base + 16] = f2bf(e1 * inv);
        }
      } else if (sec == 1) {                 // exp(k) (no max-sub: k ~ N(0,1))
#pragma unroll
        for (int r = 0; r < 4; r++) {
          long base = (row0 + r) * 128 + sc + c;
          dstp[base]      = f2bf(__expf(a0[r]));
          dstp[base + 16] = f2bf(__expf(a1[r]));
        }
      } else {                               // raw v (1/N folded into ctx normalize)
#pragma unroll
        for (int r = 0; r < 4; r++) {
          long base = (row0 + r) * 128 + sc + c;
          dstp[base]      = f2bf(a0[r]);
          dstp[base + 16] = f2bf(a1[r]);
        }
      }
    }
  }
}

// ---------------- k_ctx: chunk partials of EK^T·V and sum-exp ----------------
// grid (16 chunks, 32 batches) x 256 thr; wave = head; lane owns 4x4 (d,e) tile
__global__ __launch_bounds__(256) void k_ctx(const unsigned short* __restrict__ ek,
                                             const unsigned short* __restrict__ vv,
                                             float* __restrict__ pctx,
                                             float* __restrict__ pse) {
  extern __shared__ char lds[];
  float* ekc = (float*)lds;            // [4][64][32]
  float* vcc = (float*)(lds + 32768);  // [4][64][32]

  const int tid = threadIdx.x;
  const int chunk = blockIdx.x, b = blockIdx.y;
  const long row0 = (long)b * 4096 + chunk * 256;
  const int wave = tid >> 6, lane = tid & 63;
  const int d0 = (lane >> 3) * 4, e0 = (lane & 7) * 4;
  const int nn = tid >> 2, part = tid & 3;

  f32x4 acc0 = {0.f,0.f,0.f,0.f}, acc1 = {0.f,0.f,0.f,0.f};
  f32x4 acc2 = {0.f,0.f,0.f,0.f}, acc3 = {0.f,0.f,0.f,0.f};
  f32x4 se   = {0.f,0.f,0.f,0.f};

  for (int s = 0; s < 4; s++) {
    long r = row0 + s * 64 + nn;
#pragma unroll
    for (int h = 0; h < 4; h++) {          // stage all 4 head-slices, f32
      uint4 ue = *(const uint4*)(ek + r * 128 + h * 32 + part * 8);
      uint4 uv = *(const uint4*)(vv + r * 128 + h * 32 + part * 8);
      unpack8(ue, &ekc[(h * 64 + nn) * 32 + part * 8]);
      unpack8(uv, &vcc[(h * 64 + nn) * 32 + part * 8]);
    }
    __syncthreads();
    const float* eb = &ekc[(wave * 64) * 32];
    const float* vb = &vcc[(wave * 64) * 32];
#pragma unroll 4
    for (int n = 0; n < 64; n++) {
      f32x4 ev  = *(const f32x4*)(eb + n * 32 + d0);
      f32x4 v4  = *(const f32x4*)(vb + n * 32 + e0);
      acc0 += ev.x * v4;
      acc1 += ev.y * v4;
      acc2 += ev.z * v4;
      acc3 += ev.w * v4;
      se += ev;
    }
    __syncthreads();
  }
  const long pb = ((long)chunk * 128 + b * 4 + wave) * 1024;
  *(f32x4*)&pctx[pb + (d0 + 0) * 32 + e0] = acc0;
  *(f32x4*)&pctx[pb + (d0 + 1) * 32 + e0] = acc1;
  *(f32x4*)&pctx[pb + (d0 + 2) * 32 + e0] = acc2;
  *(f32x4*)&pctx[pb + (d0 + 3) * 32 + e0] = acc3;
  if ((lane & 7) == 0)
    *(f32x4*)&pse[((long)chunk * 128 + b * 4 + wave) * 32 + d0] = se;
}

// ---------------- k_ctxred: reduce 16 chunks, normalize, emit ctx bf16 ----------------
__global__ __launch_bounds__(256) void k_ctxred(const float* __restrict__ pctx,
                                                const float* __restrict__ pse,
                                                unsigned short* __restrict__ ctxg) {
  int idx = blockIdx.x * 256 + threadIdx.x;   // 131072 = 32*4*32*32
  int de = idx & 1023, d = de >> 5, bh = idx >> 10;
  float s = 0.f, sume = 0.f;
#pragma unroll
  for (int ch = 0; ch < 16; ch++) {
    s    += pctx[(ch * 128 + bh) * 1024 + de];
    sume += pse[(ch * 128 + bh) * 32 + d];
  }
  ctxg[idx] = f2bf(s / (sume * 4096.0f));     // softmax-normalize + v's 1/N
}

// ---------------- k_out: attn = q_s·ctx ; y = attn@Wout + b ; LayerNorm ----------------
__global__ __launch_bounds__(512, 2) void k_out(const unsigned short* __restrict__ qs,
                                                const unsigned short* __restrict__ ctxg,
                                                const unsigned short* __restrict__ woT,
                                                const float* __restrict__ bout,
                                                const float* __restrict__ lnsc,
                                                float* __restrict__ out) {
  extern __shared__ char lds[];
  char* lds_wo = lds;                                       // 32768 B, swizzled [c][k]
  char* lds_at = lds + 32768;                               // 32768 B, swizzled [row][col]
  unsigned short* lds_cx = (unsigned short*)(lds + 65536);  // [4][32 e][32 d] bf16, 8192 B
  float* lds_bias  = (float*)(lds + 73728);
  float* lds_scale = (float*)(lds + 74240);

  const int tid = threadIdx.x;
  const long rowbase = (long)blockIdx.x * 128;
  const int b = blockIdx.x >> 5;

  {  // stage Wout^T
    const int4* src = (const int4*)woT;
    int4* dst = (int4*)lds_wo;
#pragma unroll
    for (int i = 0; i < 4; i++) {
      int u = tid + i * 512;
      dst[u ^ ((u >> 4) & 7)] = src[u];
    }
  }
  {  // stage ctx [h][d][e] -> LDS transposed [h][e][d]
    const unsigned int* src = (const unsigned int*)(ctxg + (long)b * 4096);
#pragma unroll
    for (int i = 0; i < 4; i++) {
      int u = tid + i * 512;           // one uint = elems (j, j+1), j = 2u
      unsigned int w = src[u];
      int j = u * 2;
      int e = j & 31, d = (j >> 5) & 31, h = j >> 10;
      lds_cx[(h * 32 + e) * 32 + d]     = (unsigned short)(w & 0xffffu);
      lds_cx[(h * 32 + e + 1) * 32 + d] = (unsigned short)(w >> 16);
    }
  }
  if (tid < 128) { lds_bias[tid] = bout[tid]; lds_scale[tid] = lnsc[tid]; }
  __syncthreads();

  const int lane = tid & 63, g = lane >> 4, c = lane & 15;
  const int wave = tid >> 6;

  // GEMM1: attn[16 rows][128] ; A = q_s straight from global (L2), B = ctx from LDS
  f32x4 acc1[4][2];
#pragma unroll
  for (int h = 0; h < 4; h++) { acc1[h][0] = (f32x4){0.f,0.f,0.f,0.f}; acc1[h][1] = (f32x4){0.f,0.f,0.f,0.f}; }
  const unsigned short* qrow = qs + (rowbase + wave * 16 + c) * 128;
#pragma unroll
  for (int h = 0; h < 4; h++) {
    bf16x8 a = *(const bf16x8*)(qrow + h * 32 + g * 8);
#pragma unroll
    for (int et = 0; et < 2; et++) {
      bf16x8 bq = *(const bf16x8*)(lds_cx + (h * 32 + et * 16 + c) * 32 + g * 8);
      acc1[h][et] = __builtin_amdgcn_mfma_f32_16x16x32_bf16(a, bq, acc1[h][et], 0, 0, 0);
    }
  }
  {  // attn -> LDS (bf16, swizzled) for the A-fragment round trip
    int rowl = wave * 16 + g * 4;
#pragma unroll
    for (int h = 0; h < 4; h++)
#pragma unroll
      for (int et = 0; et < 2; et++) {
        int col = (2 * h + et) * 16 + c;
#pragma unroll
        for (int r = 0; r < 4; r++) {
          int row = rowl + r;
          int ba = (row * 256 + col * 2) ^ ((row & 7) << 4);
          *(unsigned short*)(lds_at + ba) = f2bf(acc1[h][et][r]);
        }
      }
  }
  __syncthreads();

  // GEMM2: y = attn @ Wout
  f32x4 acc2[8];
#pragma unroll
  for (int ct = 0; ct < 8; ct++) acc2[ct] = (f32x4){0.f,0.f,0.f,0.f};
#pragma unroll
  for (int kk = 0; kk < 4; kk++) {
    int koff = (kk * 32 + g * 8) * 2;
    int arow = wave * 16 + c;
    bf16x8 a = *(const bf16x8*)(lds_at + ((arow * 256 + koff) ^ ((arow & 7) << 4)));
#pragma unroll
    for (int ct = 0; ct < 8; ct++) {
      int wrow = ct * 16 + c;
      bf16x8 bw = *(const bf16x8*)(lds_wo + ((wrow * 256 + koff) ^ ((wrow & 7) << 4)));
      acc2[ct] = __builtin_amdgcn_mfma_f32_16x16x32_bf16(a, bw, acc2[ct], 0, 0, 0);
    }
  }

  // bias + LayerNorm (per-row over 128 channels, shuffle reduction)
  float biasv[8], scalev[8];
#pragma unroll
  for (int ct = 0; ct < 8; ct++) { biasv[ct] = lds_bias[ct * 16 + c]; scalev[ct] = lds_scale[ct * 16 + c]; }
#pragma unroll
  for (int ct = 0; ct < 8; ct++)
#pragma unroll
    for (int r = 0; r < 4; r++)
      acc2[ct][r] += biasv[ct];

#pragma unroll
  for (int r = 0; r < 4; r++) {
    float s = 0.f, ss = 0.f;
#pragma unroll
    for (int ct = 0; ct < 8; ct++) { float v = acc2[ct][r]; s += v; ss += v * v; }
    s  += __shfl_xor(s, 1);  s  += __shfl_xor(s, 2);  s  += __shfl_xor(s, 4);  s  += __shfl_xor(s, 8);
    ss += __shfl_xor(ss, 1); ss += __shfl_xor(ss, 2); ss += __shfl_xor(ss, 4); ss += __shfl_xor(ss, 8);
    float mu = s * 0.0078125f;
    float var = ss * 0.0078125f - mu * mu;
    float rstd = rsqrtf(var + 1e-5f);
    long row = rowbase + wave * 16 + g * 4 + r;
#pragma unroll
    for (int ct = 0; ct < 8; ct++)
      out[row * 128 + ct * 16 + c] = (acc2[ct][r] - mu) * rstd * scalev[ct];
  }
}

// ---------------- host ----------------
extern "C" void kernel_launch(void* const* d_in, const int* in_sizes, int n_in,
                              void* d_out, int out_size, void* d_ws, size_t ws_size,
                              hipStream_t stream) {
  (void)in_sizes; (void)n_in; (void)out_size; (void)ws_size;
  const float* x     = (const float*)d_in[0];
  const float* wqkv  = (const float*)d_in[1];
  const float* wout  = (const float*)d_in[2];
  const float* bo    = (const float*)d_in[3];
  const float* lnsc  = (const float*)d_in[4];
  float* out = (float*)d_out;

  char* ws = (char*)d_ws;
  unsigned short* qs   = (unsigned short*)(ws + OFF_QS);
  unsigned short* ek   = (unsigned short*)(ws + OFF_EK);
  unsigned short* vv   = (unsigned short*)(ws + OFF_VV);
  float*          pctx = (float*)(ws + OFF_PCTX);
  float*          pse  = (float*)(ws + OFF_PSE);
  unsigned short* ctxg = (unsigned short*)(ws + OFF_CTXG);
  unsigned short* wqT  = (unsigned short*)(ws + OFF_WQT);
  unsigned short* woT  = (unsigned short*)(ws + OFF_WOT);

  k_prep<<<dim3(256), dim3(256), 0, stream>>>(wqkv, wout, wqT, woT);
  k_qkv<<<dim3(1024), dim3(512), 131072, stream>>>(x, wqT, qs, ek, vv);
  k_ctx<<<dim3(16, 32), dim3(256), 65536, stream>>>(ek, vv, pctx, pse);
  k_ctxred<<<dim3(512), dim3(256), 0, stream>>>(pctx, pse, ctxg);
  k_out<<<dim3(1024), dim3(512), 74752, stream>>>(qs, ctxg, woT, bo, lnsc, out);
}